// Round 7
// baseline (787.341 us; speedup 1.0000x reference)
//
#include <hip/hip_runtime.h>

typedef unsigned short u16t;
typedef __attribute__((ext_vector_type(8))) short bf16x8;
typedef __attribute__((ext_vector_type(4))) float f32x4;

__device__ __forceinline__ float bf2f(u16t u) {
  union { unsigned int i; float f; } v; v.i = ((unsigned int)u) << 16; return v.f;
}
__device__ __forceinline__ u16t f2bf(float f) {
  union { float f; unsigned int i; } v; v.f = f;
  return (u16t)((v.i + 0x7fffu + ((v.i >> 16) & 1u)) >> 16);
}
__device__ __forceinline__ float sigm(float x) { return 1.0f / (1.0f + __expf(-x)); }
__device__ __forceinline__ float tanh_f(float x) { return 1.0f - 2.0f / (__expf(2.0f * x) + 1.0f); }
__device__ __forceinline__ float lrelu(float x) { return x > 0.0f ? x : 0.2f * x; }

__device__ __forceinline__ float ldf(const void* p, long i, bool isbf) {
  return isbf ? bf2f(((const u16t*)p)[i]) : ((const float*)p)[i];
}
__device__ __forceinline__ bf16x8 ld8(const void* p, long i, bool isbf) {
  if (isbf) return *reinterpret_cast<const bf16x8*>((const u16t*)p + i);
  const float* f = (const float*)p + i;
  bf16x8 r;
  #pragma unroll
  for (int j = 0; j < 8; ++j) r[j] = (short)f2bf(f[j]);
  return r;
}
__device__ __forceinline__ bool sniff_bf(const void* h_g) {
  bool isbf = true;
  #pragma unroll
  for (int i = 0; i < 16; ++i) {
    u16t u = ((const u16t*)h_g)[2 * i];
    int e = (u >> 7) & 0xFF;
    if (e < 100 || e > 142) isbf = false;
  }
  return isbf;
}

#define MFMA16(a, b, c) __builtin_amdgcn_mfma_f32_16x16x32_bf16((a), (b), (c), 0, 0, 0)

#define DDIM 128
#define SD 136   // s/a tiles: 64 rows x 128 + 8 pad (2-way bank alias = free)
#define ST 72    // mT / attn tiles: +8 pad
#define R0_OFF 0
#define R1_OFF 9216
#define R2_OFF 18432
#define AT_OFF 27648
#define NLDS   32256   // 64512 B (+768 B floats) -> 2 blocks/CU

// ws layout (bf16), fragment-major: one wave's fragment = 1 KB contiguous
#define WS_W_OFF   0
#define WS_IH_OFF  16384
#define WS_HH_OFF  65536
#define WS_M1_OFF  114688
#define WS_ELEMS   122880

__global__ __launch_bounds__(256) void prep(
    const void* __restrict__ h_g, const void* __restrict__ w_g,
    const void* __restrict__ wih_g, const void* __restrict__ whh_g,
    const void* __restrict__ m1w_g, u16t* __restrict__ ws) {
  const bool isbf = sniff_bf(h_g);
  const int idx = blockIdx.x * 256 + threadIdx.x;
  if (idx >= WS_ELEMS) return;
  float val;
  if (idx < WS_IH_OFF) {
    int t = idx;
    int j = t & 7, lane = (t >> 3) & 63, ks = (t >> 9) & 3, wv = t >> 11;
    val = ldf(w_g, (long)(ks * 32 + (lane >> 4) * 8 + j) * DDIM + wv * 16 + (lane & 15), isbf);
  } else if (idx < WS_HH_OFF) {
    int t = idx - WS_IH_OFF;
    int j = t & 7, lane = (t >> 3) & 63, ks = (t >> 9) & 3, rem = t >> 11;
    int g = rem % 3, wv = rem / 3;
    val = ldf(wih_g, (long)(g * 128 + wv * 16 + (lane & 15)) * DDIM + ks * 32 + (lane >> 4) * 8 + j, isbf);
  } else if (idx < WS_M1_OFF) {
    int t = idx - WS_HH_OFF;
    int j = t & 7, lane = (t >> 3) & 63, ks = (t >> 9) & 3, rem = t >> 11;
    int g = rem % 3, wv = rem / 3;
    val = ldf(whh_g, (long)(g * 128 + wv * 16 + (lane & 15)) * DDIM + ks * 32 + (lane >> 4) * 8 + j, isbf);
  } else {
    int t = idx - WS_M1_OFF;
    int j = t & 7, lane = (t >> 3) & 63, ks = (t >> 9) & 3, wv = t >> 11;
    val = ldf(m1w_g, (long)(ks * 32 + (lane >> 4) * 8 + j) * 64 + wv * 16 + (lane & 15), isbf);
  }
  ws[idx] = f2bf(val);
}

// REG NOTE (r6): allocator pins 128 VGPRs; r6 spilled ~7 regs (WRITE 57 MB)
// because rg16/zg16 were 32 live u16 regs through the n-phase. r7 packs them
// 2-per-uint (16 regs) and prefetches ws B-frags in batches per ks so the
// freed slack turns L2 latency into overlap.
template <bool WSOK>
__global__ __launch_bounds__(512) void fignn(
    const void* __restrict__ h_g, const void* __restrict__ asrc_g,
    const void* __restrict__ adst_g, const void* __restrict__ w_g,
    const void* __restrict__ bias_g, const void* __restrict__ wih_g,
    const void* __restrict__ whh_g, const void* __restrict__ bih_g,
    const void* __restrict__ bhh_g, const void* __restrict__ m1w_g,
    const void* __restrict__ m1b_g, const void* __restrict__ m2w_g,
    const void* __restrict__ m2b_g, const int* __restrict__ steps_p,
    const u16t* __restrict__ ws_g, void* __restrict__ out_g) {
  __shared__ __align__(16) u16t lds[NLDS];
  __shared__ __align__(16) float ldsf[192];
  u16t* sh_at = lds + AT_OFF;
  float* f_src = ldsf;
  float* f_dst = ldsf + 64;
  float* f_wv  = ldsf + 128;

  const int tid  = threadIdx.x;
  const int wv   = tid >> 6;
  const int lane = tid & 63;
  const int quad = lane >> 4;
  const int lrow = lane & 15;
  const int col  = wv * 16 + lrow;  // feature column (N-split across 8 waves)
  const int b    = blockIdx.x;

  const bool isbf = sniff_bf(h_g);

  u16t* s_c = lds + R0_OFF;  // current s
  u16t* s_m = lds + R1_OFF;  // mT, then s_next
  u16t* s_a = lds + R2_OFF;  // message a

  // per-wave ws fragment base pointers (1 KB per fragment)
  const u16t* ws_w  = ws_g + WS_W_OFF  + (((wv * 4)  * 64 + lane) << 3);  // +ks*512
  const u16t* ws_ih = ws_g + WS_IH_OFF + (((wv * 12) * 64 + lane) << 3);  // +(g*4+ks)*512
  const u16t* ws_hh = ws_g + WS_HH_OFF + (((wv * 12) * 64 + lane) << 3);
  const u16t* ws_m1 = ws_g + WS_M1_OFF + (((wv * 4)  * 64 + lane) << 3);

  // ---- stage h -> s_c (s0 = h) ----
  const long hb = (long)b * (64 * DDIM);
  #pragma unroll
  for (int v = 0; v < 2; ++v) {
    int e = (tid + v * 512) * 8;
    int r = e >> 7, c = e & 127;
    *reinterpret_cast<bf16x8*>(s_c + r * SD + c) = ld8(h_g, hb + e, isbf);
  }

  // ---- per-thread packed h / s registers (2 bf16 per uint) ----
  unsigned int sreg2[8], hreg2[8];
  #pragma unroll
  for (int mt = 0; mt < 4; ++mt) {
    #pragma unroll
    for (int half = 0; half < 2; ++half) {
      u16t lo = f2bf(ldf(h_g, hb + (mt * 16 + quad * 4 + half * 2 + 0) * DDIM + col, isbf));
      u16t hi = f2bf(ldf(h_g, hb + (mt * 16 + quad * 4 + half * 2 + 1) * DDIM + col, isbf));
      unsigned int p = (unsigned int)lo | ((unsigned int)hi << 16);
      hreg2[mt * 2 + half] = p;
      sreg2[mt * 2 + half] = p;
    }
  }

  const float msg_b = ldf(bias_g, col, isbf);
  const float bsum_r = ldf(bih_g, col, isbf) + ldf(bhh_g, col, isbf);
  const float bsum_z = ldf(bih_g, 128 + col, isbf) + ldf(bhh_g, 128 + col, isbf);
  const float b_in   = ldf(bih_g, 256 + col, isbf);
  const float b_hn   = ldf(bhh_g, 256 + col, isbf);
  int steps = *steps_p;
  if (steps < 1 || steps > 64) steps = 3;
  __syncthreads();

  // ---- attention dots (128 threads: 2 per node) ----
  if (tid < 128) {
    const int node = tid >> 1, half = tid & 1;
    float sa = 0.f, da = 0.f;
    #pragma unroll
    for (int k = half * 64; k < half * 64 + 64; k += 8) {
      bf16x8 hv = *reinterpret_cast<const bf16x8*>(s_c + node * SD + k);
      #pragma unroll
      for (int j = 0; j < 8; ++j) {
        float hf = bf2f((u16t)hv[j]);
        sa += hf * ldf(asrc_g, k + j, isbf);
        da += hf * ldf(adst_g, k + j, isbf);
      }
    }
    sa += __shfl_xor(sa, 1);
    da += __shfl_xor(da, 1);
    if (half == 0) { f_src[node] = sa; f_dst[node] = da; }
  }
  __syncthreads();
  // ---- masked-diagonal softmax, 8 threads per row ----
  {
    const int row = tid >> 3, sub = tid & 7;
    const float si = f_src[row];
    float vals[8];
    float mx = 0.0f;  // diagonal (masked) entry is exactly 0, part of the row
    #pragma unroll
    for (int u = 0; u < 8; ++u) {
      int j = sub + u * 8;
      float vv = (j == row) ? 0.0f : lrelu(si + f_dst[j]);
      vals[u] = vv;
      mx = fmaxf(mx, vv);
    }
    mx = fmaxf(mx, __shfl_xor(mx, 1));
    mx = fmaxf(mx, __shfl_xor(mx, 2));
    mx = fmaxf(mx, __shfl_xor(mx, 4));
    float sum = 0.f;
    #pragma unroll
    for (int u = 0; u < 8; ++u) { vals[u] = __expf(vals[u] - mx); sum += vals[u]; }
    sum += __shfl_xor(sum, 1);
    sum += __shfl_xor(sum, 2);
    sum += __shfl_xor(sum, 4);
    float inv = 1.0f / sum;
    #pragma unroll
    for (int u = 0; u < 8; ++u)
      sh_at[row * ST + sub + u * 8] = f2bf(vals[u] * inv);
  }
  __syncthreads();

  // ---- message-passing + GRU steps (2 barriers/step) ----
  for (int it = 0; it < steps; ++it) {
    // GEMM1: mT[col][*] = (s @ w)[:, col] -> s_m (wave-local, packed)
    {
      f32x4 macc[4] = {{0,0,0,0},{0,0,0,0},{0,0,0,0},{0,0,0,0}};
      #pragma unroll
      for (int ks = 0; ks < 4; ++ks) {
        bf16x8 bw;
        if constexpr (WSOK) {
          bw = *reinterpret_cast<const bf16x8*>(ws_w + (ks << 9));
        } else {
          #pragma unroll
          for (int j = 0; j < 8; ++j)
            bw[j] = (short)f2bf(ldf(w_g, (long)(ks * 32 + quad * 8 + j) * DDIM + col, isbf));
        }
        #pragma unroll
        for (int mt = 0; mt < 4; ++mt) {
          bf16x8 af = *reinterpret_cast<const bf16x8*>(s_c + (mt * 16 + lrow) * SD + ks * 32 + quad * 8);
          macc[mt] = MFMA16(af, bw, macc[mt]);
        }
      }
      #pragma unroll
      for (int mt = 0; mt < 4; ++mt) {
        ushort4 pk;
        pk.x = f2bf(macc[mt][0]); pk.y = f2bf(macc[mt][1]);
        pk.z = f2bf(macc[mt][2]); pk.w = f2bf(macc[mt][3]);
        *reinterpret_cast<ushort4*>(s_m + col * ST + mt * 16 + quad * 4) = pk;
      }
    }
    // GEMM2: a[:, col] = (attn @ m)[:, col] + bias -> s_a (intra-wave mT read)
    #pragma unroll
    for (int mt = 0; mt < 4; ++mt) {
      f32x4 acc = {0.f, 0.f, 0.f, 0.f};
      #pragma unroll
      for (int ks = 0; ks < 2; ++ks) {
        bf16x8 af  = *reinterpret_cast<const bf16x8*>(sh_at + (mt * 16 + lrow) * ST + ks * 32 + quad * 8);
        bf16x8 bfv = *reinterpret_cast<const bf16x8*>(s_m + col * ST + ks * 32 + quad * 8);
        acc = MFMA16(af, bfv, acc);
      }
      #pragma unroll
      for (int r = 0; r < 4; ++r)
        s_a[(mt * 16 + quad * 4 + r) * SD + col] = f2bf(acc[r] + msg_b);
    }
    __syncthreads();  // (1) a ready; all mT reads done

    // Phase rz: r,z gate pre-activations (gi+gh combined); results packed bf16x2
    unsigned int rgp[8], zgp[8];
    {
      f32x4 ar[4] = {{0,0,0,0},{0,0,0,0},{0,0,0,0},{0,0,0,0}};
      f32x4 az[4] = {{0,0,0,0},{0,0,0,0},{0,0,0,0},{0,0,0,0}};
      #pragma unroll
      for (int ks = 0; ks < 4; ++ks) {
        // batch the 4 independent L2 fragment loads up front (latency overlap)
        bf16x8 bw_ir, bw_iz, bw_hr, bw_hz;
        if constexpr (WSOK) {
          bw_ir = *reinterpret_cast<const bf16x8*>(ws_ih + ((0 * 4 + ks) << 9));
          bw_iz = *reinterpret_cast<const bf16x8*>(ws_ih + ((1 * 4 + ks) << 9));
          bw_hr = *reinterpret_cast<const bf16x8*>(ws_hh + ((0 * 4 + ks) << 9));
          bw_hz = *reinterpret_cast<const bf16x8*>(ws_hh + ((1 * 4 + ks) << 9));
        } else {
          bw_ir = ld8(wih_g, (long)(0 * 128 + col) * DDIM + ks * 32 + quad * 8, isbf);
          bw_iz = ld8(wih_g, (long)(1 * 128 + col) * DDIM + ks * 32 + quad * 8, isbf);
          bw_hr = ld8(whh_g, (long)(0 * 128 + col) * DDIM + ks * 32 + quad * 8, isbf);
          bw_hz = ld8(whh_g, (long)(1 * 128 + col) * DDIM + ks * 32 + quad * 8, isbf);
        }
        bf16x8 fa[4];
        #pragma unroll
        for (int mt = 0; mt < 4; ++mt)
          fa[mt] = *reinterpret_cast<const bf16x8*>(s_a + (mt * 16 + lrow) * SD + ks * 32 + quad * 8);
        #pragma unroll
        for (int mt = 0; mt < 4; ++mt) ar[mt] = MFMA16(fa[mt], bw_ir, ar[mt]);
        #pragma unroll
        for (int mt = 0; mt < 4; ++mt) az[mt] = MFMA16(fa[mt], bw_iz, az[mt]);
        #pragma unroll
        for (int mt = 0; mt < 4; ++mt)
          fa[mt] = *reinterpret_cast<const bf16x8*>(s_c + (mt * 16 + lrow) * SD + ks * 32 + quad * 8);
        #pragma unroll
        for (int mt = 0; mt < 4; ++mt) ar[mt] = MFMA16(fa[mt], bw_hr, ar[mt]);
        #pragma unroll
        for (int mt = 0; mt < 4; ++mt) az[mt] = MFMA16(fa[mt], bw_hz, az[mt]);
      }
      #pragma unroll
      for (int mt = 0; mt < 4; ++mt) {
        #pragma unroll
        for (int hf = 0; hf < 2; ++hf) {
          unsigned int rl = f2bf(sigm(ar[mt][hf * 2 + 0] + bsum_r));
          unsigned int rh = f2bf(sigm(ar[mt][hf * 2 + 1] + bsum_r));
          unsigned int zl = f2bf(sigm(az[mt][hf * 2 + 0] + bsum_z));
          unsigned int zh = f2bf(sigm(az[mt][hf * 2 + 1] + bsum_z));
          rgp[mt * 2 + hf] = rl | (rh << 16);
          zgp[mt * 2 + hf] = zl | (zh << 16);
        }
      }
    }
    // Phase n + pointwise GRU; snew -> s_m (mT dead after barrier 1)
    {
      f32x4 ain[4] = {{0,0,0,0},{0,0,0,0},{0,0,0,0},{0,0,0,0}};
      f32x4 ahn[4] = {{0,0,0,0},{0,0,0,0},{0,0,0,0},{0,0,0,0}};
      #pragma unroll
      for (int ks = 0; ks < 4; ++ks) {
        bf16x8 bw_in, bw_hn;
        if constexpr (WSOK) {
          bw_in = *reinterpret_cast<const bf16x8*>(ws_ih + ((2 * 4 + ks) << 9));
          bw_hn = *reinterpret_cast<const bf16x8*>(ws_hh + ((2 * 4 + ks) << 9));
        } else {
          bw_in = ld8(wih_g, (long)(2 * 128 + col) * DDIM + ks * 32 + quad * 8, isbf);
          bw_hn = ld8(whh_g, (long)(2 * 128 + col) * DDIM + ks * 32 + quad * 8, isbf);
        }
        bf16x8 fr[4];
        #pragma unroll
        for (int mt = 0; mt < 4; ++mt)
          fr[mt] = *reinterpret_cast<const bf16x8*>(s_a + (mt * 16 + lrow) * SD + ks * 32 + quad * 8);
        #pragma unroll
        for (int mt = 0; mt < 4; ++mt) ain[mt] = MFMA16(fr[mt], bw_in, ain[mt]);
        #pragma unroll
        for (int mt = 0; mt < 4; ++mt)
          fr[mt] = *reinterpret_cast<const bf16x8*>(s_c + (mt * 16 + lrow) * SD + ks * 32 + quad * 8);
        #pragma unroll
        for (int mt = 0; mt < 4; ++mt) ahn[mt] = MFMA16(fr[mt], bw_hn, ahn[mt]);
      }
      #pragma unroll
      for (int mt = 0; mt < 4; ++mt) {
        #pragma unroll
        for (int r = 0; r < 4; ++r) {
          unsigned int rp = rgp[mt * 2 + (r >> 1)];
          unsigned int zp = zgp[mt * 2 + (r >> 1)];
          float rg = bf2f((u16t)((r & 1) ? (rp >> 16) : (rp & 0xffffu)));
          float zg = bf2f((u16t)((r & 1) ? (zp >> 16) : (zp & 0xffffu)));
          float ng = tanh_f(ain[mt][r] + b_in + rg * (ahn[mt][r] + b_hn));
          unsigned int sp = sreg2[mt * 2 + (r >> 1)];
          unsigned int hp = hreg2[mt * 2 + (r >> 1)];
          float so = bf2f((u16t)((r & 1) ? (sp >> 16) : (sp & 0xffffu)));
          float hv = bf2f((u16t)((r & 1) ? (hp >> 16) : (hp & 0xffffu)));
          float sn = (1.0f - zg) * ng + zg * so + hv;
          u16t sb = f2bf(sn);
          s_m[(mt * 16 + quad * 4 + r) * SD + col] = sb;
          sreg2[mt * 2 + (r >> 1)] = (r & 1) ? ((sp & 0x0000ffffu) | ((unsigned int)sb << 16))
                                             : ((sp & 0xffff0000u) | (unsigned int)sb);
        }
      }
    }
    __syncthreads();  // (2) s_next ready
    u16t* t = s_c; s_c = s_m; s_m = s_a; s_a = t;  // rotate roles
  }

  // ---- readout: out[c] = sum_n (s@mlp2_w + b2)[n] * (s@mlp1_w + b1)[n][c] ----
  f32x4 oacc[4] = {{0,0,0,0},{0,0,0,0},{0,0,0,0},{0,0,0,0}};
  if (wv < 4) {
    #pragma unroll
    for (int ks = 0; ks < 4; ++ks) {
      bf16x8 bw;
      if constexpr (WSOK) {
        bw = *reinterpret_cast<const bf16x8*>(ws_m1 + (ks << 9));
      } else {
        #pragma unroll
        for (int j = 0; j < 8; ++j)
          bw[j] = (short)f2bf(ldf(m1w_g, (long)(ks * 32 + quad * 8 + j) * 64 + col, isbf));
      }
      #pragma unroll
      for (int mt = 0; mt < 4; ++mt) {
        bf16x8 af = *reinterpret_cast<const bf16x8*>(s_c + (mt * 16 + lrow) * SD + ks * 32 + quad * 8);
        oacc[mt] = MFMA16(af, bw, oacc[mt]);
      }
    }
    const float b1c = ldf(m1b_g, col, isbf);
    #pragma unroll
    for (int mt = 0; mt < 4; ++mt)
      #pragma unroll
      for (int r = 0; r < 4; ++r) oacc[mt][r] += b1c;
  } else if (wv == 4) {
    float acc = 0.f;
    #pragma unroll
    for (int k = 0; k < 128; k += 8) {
      bf16x8 sv = *reinterpret_cast<const bf16x8*>(s_c + lane * SD + k);
      #pragma unroll
      for (int j = 0; j < 8; ++j) acc += bf2f((u16t)sv[j]) * ldf(m2w_g, k + j, isbf);
    }
    f_wv[lane] = acc + ldf(m2b_g, 0, isbf);
  }
  __syncthreads();
  if (wv < 4) {
    float p = 0.f;
    #pragma unroll
    for (int mt = 0; mt < 4; ++mt)
      #pragma unroll
      for (int r = 0; r < 4; ++r)
        p += f_wv[mt * 16 + quad * 4 + r] * oacc[mt][r];
    p += __shfl_xor(p, 16);
    p += __shfl_xor(p, 32);
    if (quad == 0) {
      if (isbf) ((u16t*)out_g)[(long)b * 64 + col] = f2bf(p);
      else      ((float*)out_g)[(long)b * 64 + col] = p;
    }
  }
}

extern "C" void kernel_launch(void* const* d_in, const int* in_sizes, int n_in,
                              void* d_out, int out_size, void* d_ws, size_t ws_size,
                              hipStream_t stream) {
  (void)in_sizes; (void)n_in; (void)out_size;
  // d_in order: h, adj(unused), a_src, a_dst, w, bias, W_ih, W_hh, b_ih, b_hh,
  //             mlp1_w, mlp1_b, mlp2_w, mlp2_b, steps
  const bool wsok = ws_size >= (size_t)WS_ELEMS * 2;
  if (wsok) {
    prep<<<dim3((WS_ELEMS + 255) / 256), dim3(256), 0, stream>>>(
        d_in[0], d_in[4], d_in[6], d_in[7], d_in[10], (u16t*)d_ws);
    fignn<true><<<dim3(4096), dim3(512), 0, stream>>>(
        d_in[0], d_in[2], d_in[3], d_in[4], d_in[5], d_in[6], d_in[7], d_in[8],
        d_in[9], d_in[10], d_in[11], d_in[12], d_in[13], (const int*)d_in[14],
        (const u16t*)d_ws, d_out);
  } else {
    fignn<false><<<dim3(4096), dim3(512), 0, stream>>>(
        d_in[0], d_in[2], d_in[3], d_in[4], d_in[5], d_in[6], d_in[7], d_in[8],
        d_in[9], d_in[10], d_in[11], d_in[12], d_in[13], (const int*)d_in[14],
        (const u16t*)d_ws, d_out);
  }
}